// Round 7
// baseline (146.982 us; speedup 1.0000x reference)
//
#include <hip/hip_runtime.h>
#include <hip/hip_bf16.h>

// out[b, l, c] = data[(cycle_index[b] % CYC + l) % CYC, c]
// B=4096, L=720, C=64 fp32. ~755MB streaming writes -> write-BW bound.
// R7: R5's register-preload structure + R6's PLAIN stores (NT was the cap).
// src_k = (start + lofs + 16k) % 168 has PERIOD 21, so each thread's 45
// stores draw from 21 registers. Steady-state loop = pure reg->store
// stream (store-only LSU traffic, same as the 6.7TB/s fill kernel).

typedef float f4_t __attribute__((ext_vector_type(4)));

#define B_      4096
#define L_      720
#define C4_     16        // 64 floats / 4
#define CYC_    168
#define LPB_    16        // l-values per block-pass (256 thr = 16 l x 16 c4)
#define CHUNKS_ (L_ / LPB_)          // 45 (exact)
#define PERIOD_ 21                   // stride-16 cycle length mod 168

__global__ __launch_bounds__(256) void rc_kernel_fixed(
    const int* __restrict__ cycle_index,
    const f4_t* __restrict__ data4,    // [CYC][C4]
    f4_t* __restrict__ out4)           // [B][L][C4]
{
    const int t    = threadIdx.x;
    const int lofs = t >> 4;            // 0..15
    const int c4   = t & 15;            // 0..15

    for (int b = blockIdx.x; b < B_; b += gridDim.x) {
        const int start = cycle_index[b] % CYC_;

        int src = start + lofs;                    // < 184
        if (src >= CYC_) src -= CYC_;

        // Preload the 21-periodic table values for this (b, lofs, c4).
        f4_t r[PERIOD_];
        #pragma unroll
        for (int j = 0; j < PERIOD_; ++j) {
            r[j] = data4[src * C4_ + c4];          // L1-resident 43KB table
            src += LPB_;
            if (src >= CYC_) src -= CYC_;
        }

        // Pure store stream: 45 independent dwordx4 through L2.
        f4_t* outp = out4 + (size_t)b * (L_ * C4_) + t;
        #pragma unroll
        for (int k = 0; k < CHUNKS_; ++k) {
            outp[0] = r[k % PERIOD_];              // compile-time index
            outp += 256;                           // +4KB per block-pass
        }
    }
}

// Generic fallback (any B/L): grid-stride chunks, plain stores.
__global__ __launch_bounds__(256) void rc_kernel_generic(
    const int* __restrict__ cycle_index,
    const f4_t* __restrict__ data4,
    f4_t* __restrict__ out4,
    int L, int chunks, int nchunk_total)
{
    const int t    = threadIdx.x;
    const int lofs = t >> 4;
    const int c4   = t & 15;

    for (int chunk = blockIdx.x; chunk < nchunk_total; chunk += gridDim.x) {
        const int b  = chunk / chunks;
        const int lc = chunk - b * chunks;
        const int l  = lc * LPB_ + lofs;
        if (l >= L) continue;

        const int start = cycle_index[b] % CYC_;
        int src = start + l;
        src %= CYC_;

        const f4_t v = data4[src * C4_ + c4];
        out4[((size_t)b * (size_t)L + l) * C4_ + c4] = v;
    }
}

extern "C" void kernel_launch(void* const* d_in, const int* in_sizes, int n_in,
                              void* d_out, int out_size, void* d_ws, size_t ws_size,
                              hipStream_t stream) {
    const int*   cycle_index = (const int*)d_in[0];
    const float* data        = (const float*)d_in[2];

    const int B = in_sizes[0];
    const int L = out_size / (B * 64);

    const int grid = 2048;  // 256 CU x 8 blocks; 2 b's per block at B=4096

    if (B == B_ && L == L_) {
        rc_kernel_fixed<<<grid, 256, 0, stream>>>(
            cycle_index, (const f4_t*)data, (f4_t*)d_out);
    } else {
        const int chunks = (L + LPB_ - 1) / LPB_;
        const int nchunk = B * chunks;
        rc_kernel_generic<<<grid, 256, 0, stream>>>(
            cycle_index, (const f4_t*)data, (f4_t*)d_out,
            L, chunks, nchunk);
    }
}